// Round 1
// baseline (918.757 us; speedup 1.0000x reference)
//
#include <hip/hip_runtime.h>

// Problem constants (from reference): 16 clouds x 4096 pts, sample 1024, D=512
#define N_PER   4096
#define M_SAMP  1024
#define B_CL    16
#define D_FEAT  512
#define TPB     256
#define NWAVE   (TPB / 64)      // 4 waves
#define PPT     (N_PER / TPB)   // 16 points per thread
#define NPAIR   (PPT / 2)       // 8 packed pairs per thread

typedef float v2f __attribute__((ext_vector_type(2)));

// ---------------------------------------------------------------------------
// DPP u64-key argmax combine. key = (float_bits(val) << 32) | (tag | (4095-idx)):
//   max key == max val; tie -> min idx  (exact jnp.argmax first-occurrence).
// Tag bits [21:12] of the low word are the iteration number, identical across
// all lanes/waves of one iteration, so they do not perturb the ordering.
// ---------------------------------------------------------------------------
template <int CTRL>
__device__ __forceinline__ void dpp_combine2(unsigned& khi, unsigned& klo) {
    unsigned h2 = (unsigned)__builtin_amdgcn_update_dpp((int)khi, (int)khi, CTRL, 0xF, 0xF, false);
    unsigned l2 = (unsigned)__builtin_amdgcn_update_dpp((int)klo, (int)klo, CTRL, 0xF, 0xF, false);
    unsigned long long k  = ((unsigned long long)khi << 32) | klo;
    unsigned long long k2 = ((unsigned long long)h2  << 32) | l2;
    if (k2 > k) { khi = h2; klo = l2; }
}

// ---------------------------------------------------------------------------
// FPS: one workgroup per cloud, 256 threads. waves_per_eu(1,1): only 16 blocks
// exist chip-wide, so occupancy is worthless -- give each wave the full VGPR
// budget so px/py/pz/dist stay in real VGPRs.
//
// BARRIER-FREE iteration rhythm: instead of ds_write + __syncthreads + read,
// each wave's lane63 writes its winner key (with iteration tag embedded in
// lo[21:12]) into a double-buffered LDS slot set, then ALL waves spin-read the
// 4 slots until every tag matches the current iteration. This fuses the sync
// with the key-broadcast read into one LDS round and removes 1023 barrier
// drains/rendezvous from the serial dependence chain.
//   Skew proof: a wave writes slot set (s+2)&1 only after its spin on s+1
//   passed => all waves wrote s+1 => all waves passed spin s => nobody still
//   reads slot set s&1. So double-buffering is race-free.
//   Tear guard: only the init(0)->first-write transition could expose a torn
//   key; legitimate keys always have hi != 0 (a wave's max dist is 0 only if
//   all its 1024 points were already sampled - impossible), so hi==0 repolls.
// ---------------------------------------------------------------------------
__global__ __launch_bounds__(TPB)
__attribute__((amdgpu_waves_per_eu(1, 1)))
void fps_kernel(const float* __restrict__ pos, int* __restrict__ sidx) {
    __shared__ float4             spos[N_PER];     // 64 KiB coord table
    __shared__ unsigned long long sw[2][NWAVE];    // double-buffered wave keys
    __shared__ int                sloc[M_SAMP];    // sampled local indices

    const int cloud = blockIdx.x;
    const int tid   = threadIdx.x;
    const float* posb = pos + (size_t)cloud * N_PER * 3;

    // preload my 16 points (12 aligned float4 from global), pack into v2f regs,
    // and stage the same points into spos (one-time; bank conflicts negligible)
    v2f px2[NPAIR], py2[NPAIR], pz2[NPAIR], dist2[NPAIR];
    const int base = tid * PPT;
    {
        float f[48];
        const float4* posb4 = (const float4*)posb + tid * 12;
#pragma unroll
        for (int v = 0; v < 12; ++v) {
            float4 t = posb4[v];
            f[4 * v + 0] = t.x; f[4 * v + 1] = t.y;
            f[4 * v + 2] = t.z; f[4 * v + 3] = t.w;
        }
#pragma unroll
        for (int p = 0; p < NPAIR; ++p) {
            px2[p] = (v2f){f[6 * p + 0], f[6 * p + 3]};
            py2[p] = (v2f){f[6 * p + 1], f[6 * p + 4]};
            pz2[p] = (v2f){f[6 * p + 2], f[6 * p + 5]};
            dist2[p] = (v2f){1e30f, 1e30f};
        }
#pragma unroll
        for (int j = 0; j < PPT; ++j)
            spos[base + j] = make_float4(f[3 * j], f[3 * j + 1], f[3 * j + 2], 0.0f);
    }

    // init key slots to tag 0 (s starts at 1, so no false spin-pass)
    if (tid < 2 * NWAVE) ((unsigned long long*)sw)[tid] = 0ull;

    float lx = posb[0], ly = posb[1], lz = posb[2];   // start point = local 0
    if (tid == 0) sloc[0] = 0;

    const int wave = tid >> 6;
    const int lane = tid & 63;
    __syncthreads();   // spos + sw-init visible

    for (int s = 1; s < M_SAMP; ++s) {
        float bv = -1.0f;     // all dist >= 0, so always beaten
        int   bj = 0;
        v2f lxv = {lx, lx}, lyv = {ly, ly}, lzv = {lz, lz};
#pragma unroll
        for (int p = 0; p < NPAIR; ++p) {
#pragma clang fp contract(off)
            v2f dx = px2[p] - lxv;
            v2f dy = py2[p] - lyv;
            v2f dz = pz2[p] - lzv;
            v2f d2 = dx * dx + dy * dy + dz * dz;          // contract off: pk_mul+pk_add
            v2f dn = __builtin_elementwise_min(dist2[p], d2);
            dist2[p] = dn;
            // ascending index + strict '>' => first occurrence
            bool t0 = dn.x > bv; bv = t0 ? dn.x : bv; bj = t0 ? 2 * p     : bj;
            bool t1 = dn.y > bv; bv = t1 ? dn.y : bv; bj = t1 ? 2 * p + 1 : bj;
        }
        const unsigned tagw = (unsigned)s << 12;            // iteration tag
        unsigned khi = __float_as_uint(bv);                 // bv >= 0: bits monotone
        unsigned klo = tagw | (unsigned)(N_PER - 1 - (base + bj)); // tie -> smaller idx

        // wave64 argmax via DPP (VALU-only, 2 regs)
        dpp_combine2<0xB1>(khi, klo);    // quad_perm xor1
        dpp_combine2<0x4E>(khi, klo);    // quad_perm xor2
        dpp_combine2<0x141>(khi, klo);   // row_half_mirror
        dpp_combine2<0x140>(khi, klo);   // row_mirror
        dpp_combine2<0x142>(khi, klo);   // row_bcast15
        dpp_combine2<0x143>(khi, klo);   // row_bcast31
        // lane 63 holds the wave winner

        const int buf = s & 1;
        if (lane == 63) {
            volatile unsigned long long* slot = &sw[buf][wave];
            *slot = ((unsigned long long)khi << 32) | klo;
        }

        // spin until all 4 wave keys carry this iteration's tag (fused
        // sync + broadcast read; one LDS round in the common lockstep case)
        volatile const unsigned long long* swv = sw[buf];
        unsigned long long k0, k1, k2, k3;
        for (;;) {
            k0 = swv[0]; k1 = swv[1]; k2 = swv[2]; k3 = swv[3];
            unsigned bad = (((unsigned)k0 ^ tagw) | ((unsigned)k1 ^ tagw) |
                            ((unsigned)k2 ^ tagw) | ((unsigned)k3 ^ tagw)) & 0x3FF000u;
            bad |= (unsigned)((k0 >> 32) == 0ull) | (unsigned)((k1 >> 32) == 0ull) |
                   (unsigned)((k2 >> 32) == 0ull) | (unsigned)((k3 >> 32) == 0ull);
            if (bad == 0u) break;
        }

        // cross-wave merge (keys unique -> exact winner)
        unsigned long long k = k0;
        if (k1 > k) k = k1;
        if (k2 > k) k = k2;
        if (k3 > k) k = k3;
        int widx = N_PER - 1 - (int)(k & 0xFFFu);
        float4 wp = spos[widx];            // broadcast ds_read_b128
        lx = wp.x; ly = wp.y; lz = wp.z;
        if (tid == 0) sloc[s] = widx;      // LDS, consumed after final barrier
    }

    // dump sampled indices to global once (coalesced)
    __syncthreads();
    for (int i = tid; i < M_SAMP; i += TPB)
        sidx[cloud * M_SAMP + i] = sloc[i];
}

// ---------------------------------------------------------------------------
// Gather x rows: out[r][:] = x[g][:], float4-vectorized. 16384 rows x 128 f4.
// sidx holds LOCAL per-cloud indices; globalize with cloud offset r/M*N_PER.
// ---------------------------------------------------------------------------
__global__ __launch_bounds__(256) void gather_x_kernel(const float4* __restrict__ x4,
                                                       const int* __restrict__ sidx,
                                                       float4* __restrict__ out4) {
    int id = blockIdx.x * 256 + threadIdx.x;     // 0 .. 16384*128-1
    int r  = id >> 7;                            // row in output
    int c  = id & 127;                           // float4 column
    int g  = sidx[r] + (r >> 10 << 12);          // + (r/1024)*4096 global offset
    out4[id] = x4[(size_t)g * (D_FEAT / 4) + c];
}

// ---------------------------------------------------------------------------
// Gather pos (3 f32/row) and batch (as float). 16384 threads.
// ---------------------------------------------------------------------------
__global__ __launch_bounds__(256) void gather_pb_kernel(const float* __restrict__ pos,
                                                        const int* __restrict__ batch,
                                                        const int* __restrict__ sidx,
                                                        float* __restrict__ out_pos,
                                                        float* __restrict__ out_batch) {
    int r = blockIdx.x * 256 + threadIdx.x;      // 0 .. 16383
    int g = sidx[r] + (r >> 10 << 12);
    out_pos[r * 3 + 0] = pos[g * 3 + 0];
    out_pos[r * 3 + 1] = pos[g * 3 + 1];
    out_pos[r * 3 + 2] = pos[g * 3 + 2];
    out_batch[r] = (float)batch[g];
}

extern "C" void kernel_launch(void* const* d_in, const int* in_sizes, int n_in,
                              void* d_out, int out_size, void* d_ws, size_t ws_size,
                              hipStream_t stream) {
    const float* x     = (const float*)d_in[0];   // [65536,512] f32
    const float* pos   = (const float*)d_in[1];   // [65536,3]   f32
    const int*   batch = (const int*)d_in[2];     // [65536]     i32

    int* sidx = (int*)d_ws;                       // [16384] local sampled indices

    float* out   = (float*)d_out;
    float* out_x = out;                                            // 16384*512
    float* out_p = out + (size_t)B_CL * M_SAMP * D_FEAT;           // 16384*3
    float* out_b = out_p + (size_t)B_CL * M_SAMP * 3;              // 16384

    // 1) FPS: 16 blocks (one per cloud), 256 threads
    fps_kernel<<<B_CL, TPB, 0, stream>>>(pos, sidx);

    // 2) x gather: 16384 rows * 128 float4 / 256 threads = 8192 blocks
    gather_x_kernel<<<(B_CL * M_SAMP * (D_FEAT / 4)) / 256, 256, 0, stream>>>(
        (const float4*)x, sidx, (float4*)out_x);

    // 3) pos + batch gather: 16384 / 256 = 64 blocks
    gather_pb_kernel<<<(B_CL * M_SAMP) / 256, 256, 0, stream>>>(
        pos, batch, sidx, out_p, out_b);
}

// Round 2
// 729.698 us; speedup vs baseline: 1.2591x; 1.2591x over previous
//
#include <hip/hip_runtime.h>

// Problem constants (from reference): 16 clouds x 4096 pts, sample 1024, D=512
#define N_PER   4096
#define M_SAMP  1024
#define B_CL    16
#define D_FEAT  512
#define TPB     256
#define NWAVE   (TPB / 64)      // 4 waves
#define PPT     (N_PER / TPB)   // 16 points per thread
#define NPAIR   (PPT / 2)       // 8 packed pairs per thread

typedef float v2f __attribute__((ext_vector_type(2)));

// ---------------------------------------------------------------------------
// u32 DPP max combine (value-only wave reduce). Lanes not supplied by the
// pattern combine with themselves (old == own value -> no-op).
// ---------------------------------------------------------------------------
template <int CTRL>
__device__ __forceinline__ unsigned dpp_maxu(unsigned v) {
    unsigned o = (unsigned)__builtin_amdgcn_update_dpp((int)v, (int)v, CTRL, 0xF, 0xF, false);
    return (o > v) ? o : v;
}

// ---------------------------------------------------------------------------
// FPS: one workgroup per cloud, 256 threads, barrier-per-step rhythm (the
// verified-fastest sync structure; LDS-spin variant measured +29% worse).
//
// Per-step VALU slimming vs the 573us version:
//  - in-loop argmax tracks VALUE only via v_max3_f32 (1 instr/pair vs 6)
//  - first-occurrence index recovered post-loop by a 16-step descending
//    equality scan (interleaves into the DPP chain's latency bubbles)
//  - wave reduce is a 6-stage u32 max on float bits (dpp+v_max_u32 per
//    stage) instead of a 64-bit key reduce (dpp2+cmp_u64+2 cndmask)
//  - winner index resolved exactly via readlane(63) -> ballot -> ctz ->
//    dynamic readlane: lane order == index order, within-lane smallest j,
//    so jnp.argmax first-occurrence semantics are preserved exactly.
// Distance arithmetic identical (contract off, same op order) -> bit-exact.
// ---------------------------------------------------------------------------
__global__ __launch_bounds__(TPB)
__attribute__((amdgpu_waves_per_eu(1, 1)))
void fps_kernel(const float* __restrict__ pos, int* __restrict__ sidx) {
    __shared__ float4             spos[N_PER];     // 64 KiB coord table
    __shared__ unsigned long long sw[2][NWAVE];    // double-buffered wave keys
    __shared__ int                sloc[M_SAMP];    // sampled local indices

    const int cloud = blockIdx.x;
    const int tid   = threadIdx.x;
    const float* posb = pos + (size_t)cloud * N_PER * 3;

    // preload my 16 points (12 aligned float4 from global), pack into v2f regs,
    // and stage the same points into spos (one-time; bank conflicts negligible)
    v2f px2[NPAIR], py2[NPAIR], pz2[NPAIR], dist2[NPAIR];
    const int base = tid * PPT;
    {
        float f[48];
        const float4* posb4 = (const float4*)posb + tid * 12;
#pragma unroll
        for (int v = 0; v < 12; ++v) {
            float4 t = posb4[v];
            f[4 * v + 0] = t.x; f[4 * v + 1] = t.y;
            f[4 * v + 2] = t.z; f[4 * v + 3] = t.w;
        }
#pragma unroll
        for (int p = 0; p < NPAIR; ++p) {
            px2[p] = (v2f){f[6 * p + 0], f[6 * p + 3]};
            py2[p] = (v2f){f[6 * p + 1], f[6 * p + 4]};
            pz2[p] = (v2f){f[6 * p + 2], f[6 * p + 5]};
            dist2[p] = (v2f){1e30f, 1e30f};
        }
#pragma unroll
        for (int j = 0; j < PPT; ++j)
            spos[base + j] = make_float4(f[3 * j], f[3 * j + 1], f[3 * j + 2], 0.0f);
    }

    float lx = posb[0], ly = posb[1], lz = posb[2];   // start point = local 0
    if (tid == 0) sloc[0] = 0;

    const int wave = tid >> 6;
    const int lane = tid & 63;
    __syncthreads();   // spos visible

    for (int s = 1; s < M_SAMP; ++s) {
        float bv = -1.0f;     // all dist >= 0, so always beaten
        v2f lxv = {lx, lx}, lyv = {ly, ly}, lzv = {lz, lz};
#pragma unroll
        for (int p = 0; p < NPAIR; ++p) {
#pragma clang fp contract(off)
            v2f dx = px2[p] - lxv;
            v2f dy = py2[p] - lyv;
            v2f dz = pz2[p] - lzv;
            v2f d2 = dx * dx + dy * dy + dz * dz;          // contract off: exact jnp order
            v2f dn = __builtin_elementwise_min(dist2[p], d2);
            dist2[p] = dn;
            // value-only running max: one v_max3_f32 per pair
            asm("v_max3_f32 %0, %1, %2, %3" : "=v"(bv) : "v"(bv), "v"(dn.x), "v"(dn.y));
        }

        // first-occurrence j among my 16 slots: descending overwrite -> min j.
        // (independent of the DPP chain below; scheduler fills its bubbles)
        int bj = 0;
#pragma unroll
        for (int j = PPT - 1; j >= 0; --j) {
            float dj = (j & 1) ? dist2[j >> 1].y : dist2[j >> 1].x;
            bj = (dj == bv) ? j : bj;
        }

        // wave64 value max via u32 DPP (bv >= 0 -> float bits monotone)
        unsigned khi = __float_as_uint(bv);
        unsigned r = khi;
        r = dpp_maxu<0xB1>(r);     // quad_perm xor1
        r = dpp_maxu<0x4E>(r);     // quad_perm xor2
        r = dpp_maxu<0x141>(r);    // row_half_mirror
        r = dpp_maxu<0x140>(r);    // row_mirror
        r = dpp_maxu<0x142>(r);    // row_bcast15
        r = dpp_maxu<0x143>(r);    // row_bcast31  -> lane63 holds wave max

        unsigned smax = (unsigned)__builtin_amdgcn_readlane((int)r, 63);
        unsigned long long mask = __ballot(khi == smax);   // nonzero by construction
        int sl = __builtin_ctzll(mask);                    // first lane == lowest idx
        int widx_w = __builtin_amdgcn_readlane(base + bj, sl);  // wave winner idx

        const int buf = s & 1;
        if (lane == 0)
            sw[buf][wave] = ((unsigned long long)smax << 32) |
                            (unsigned)(N_PER - 1 - widx_w);   // tie -> min idx wins
        __syncthreads();   // only LDS outstanding -> cheap lgkm drain

        // cross-wave merge (broadcast b64 reads; keys unique -> exact winner)
        unsigned long long k = sw[buf][0];
#pragma unroll
        for (int w = 1; w < NWAVE; ++w) {
            unsigned long long k2 = sw[buf][w];
            if (k2 > k) k = k2;
        }
        int widx = N_PER - 1 - (int)(unsigned)(k & 0xFFFu);
        float4 wp = spos[widx];            // broadcast ds_read_b128
        lx = wp.x; ly = wp.y; lz = wp.z;
        if (tid == 0) sloc[s] = widx;      // LDS, drained at next barrier
    }

    // dump sampled indices to global once (coalesced)
    __syncthreads();
    for (int i = tid; i < M_SAMP; i += TPB)
        sidx[cloud * M_SAMP + i] = sloc[i];
}

// ---------------------------------------------------------------------------
// Gather x rows: out[r][:] = x[g][:], float4-vectorized. 16384 rows x 128 f4.
// sidx holds LOCAL per-cloud indices; globalize with cloud offset r/M*N_PER.
// ---------------------------------------------------------------------------
__global__ __launch_bounds__(256) void gather_x_kernel(const float4* __restrict__ x4,
                                                       const int* __restrict__ sidx,
                                                       float4* __restrict__ out4) {
    int id = blockIdx.x * 256 + threadIdx.x;     // 0 .. 16384*128-1
    int r  = id >> 7;                            // row in output
    int c  = id & 127;                           // float4 column
    int g  = sidx[r] + (r >> 10 << 12);          // + (r/1024)*4096 global offset
    out4[id] = x4[(size_t)g * (D_FEAT / 4) + c];
}

// ---------------------------------------------------------------------------
// Gather pos (3 f32/row) and batch (as float). 16384 threads.
// ---------------------------------------------------------------------------
__global__ __launch_bounds__(256) void gather_pb_kernel(const float* __restrict__ pos,
                                                        const int* __restrict__ batch,
                                                        const int* __restrict__ sidx,
                                                        float* __restrict__ out_pos,
                                                        float* __restrict__ out_batch) {
    int r = blockIdx.x * 256 + threadIdx.x;      // 0 .. 16383
    int g = sidx[r] + (r >> 10 << 12);
    out_pos[r * 3 + 0] = pos[g * 3 + 0];
    out_pos[r * 3 + 1] = pos[g * 3 + 1];
    out_pos[r * 3 + 2] = pos[g * 3 + 2];
    out_batch[r] = (float)batch[g];
}

extern "C" void kernel_launch(void* const* d_in, const int* in_sizes, int n_in,
                              void* d_out, int out_size, void* d_ws, size_t ws_size,
                              hipStream_t stream) {
    const float* x     = (const float*)d_in[0];   // [65536,512] f32
    const float* pos   = (const float*)d_in[1];   // [65536,3]   f32
    const int*   batch = (const int*)d_in[2];     // [65536]     i32

    int* sidx = (int*)d_ws;                       // [16384] local sampled indices

    float* out   = (float*)d_out;
    float* out_x = out;                                            // 16384*512
    float* out_p = out + (size_t)B_CL * M_SAMP * D_FEAT;           // 16384*3
    float* out_b = out_p + (size_t)B_CL * M_SAMP * 3;              // 16384

    // 1) FPS: 16 blocks (one per cloud), 256 threads
    fps_kernel<<<B_CL, TPB, 0, stream>>>(pos, sidx);

    // 2) x gather: 16384 rows * 128 float4 / 256 threads = 8192 blocks
    gather_x_kernel<<<(B_CL * M_SAMP * (D_FEAT / 4)) / 256, 256, 0, stream>>>(
        (const float4*)x, sidx, (float4*)out_x);

    // 3) pos + batch gather: 16384 / 256 = 64 blocks
    gather_pb_kernel<<<(B_CL * M_SAMP) / 256, 256, 0, stream>>>(
        pos, batch, sidx, out_p, out_b);
}